// Round 12
// baseline (558.838 us; speedup 1.0000x reference)
//
#include <hip/hip_runtime.h>

// Problem constants
#define BB   4
#define CIN  64
#define HH   256
#define WW   256
#define QQ   256
#define KK   16

typedef _Float16 half8 __attribute__((ext_vector_type(8)));
typedef float   f32x16 __attribute__((ext_vector_type(16)));
typedef unsigned int u32;

// ---- workspace layout (bytes); r8 proved ws_size >= 169378048 ----
#define OFF_W1R   0ull
#define OFF_W2R   294912ull
#define OFF_WMU   1474560ull
#define OFF_LGB   1490944ull
#define OFF_ACT0  1605888ull
#define OFF_ACT1  35160320ull

__device__ __forceinline__ void dma16(const void* g, void* l) {
  __builtin_amdgcn_global_load_lds(
      (const __attribute__((address_space(1))) u32*)g,
      (__attribute__((address_space(3))) u32*)l, 16, 0, 0);
}

// ---------------------------------------------------------------------------
// Prep + T0 merged. Blocks 0..575: w1r; 576..2879: w2r; 2880..2895: wmu2
// (DIRECT, no partials: one block per k, 256 coalesced w3-row iterations,
// mu scalar-uniform — kills the old k_prep2 reduction dispatch and its
// pipeline drain); 2896..2911: lgb; 2912..7007: t0 (x fp32 -> act0 fp16).
// Weight layout (global-direct B): per 16KB block (blk = cc*9+tt),
// element index = ks*4096 + n*16 + khalf*8 + e; source channel
// c = cc*32 + ks*16 + khalf*8 + e. A wave's fragment read (ks,nt) is one
// CONTIGUOUS 1KB dwordx4: byte = blk*16384 + ks*8192 + n*32 + khalf*16.
// ---------------------------------------------------------------------------
__global__ __launch_bounds__(256) void k_prep(
    const float* __restrict__ w1, const float* __restrict__ w2,
    const float* __restrict__ w3, const float* __restrict__ b3,
    const float* __restrict__ mu, const float* __restrict__ x,
    _Float16* __restrict__ w1r, _Float16* __restrict__ w2r,
    float* __restrict__ wmu2, float* __restrict__ lgb,
    _Float16* __restrict__ act0) {
  __shared__ float tile[64][65];
  __shared__ float red[256];
  int bid = blockIdx.x, tid = threadIdx.x;
  if (bid < 576) {                          // w1r (CI=64)
    int idx = bid * 256 + tid;
    int blk = idx >> 13;
    int cc = blk / 9, tt = blk - cc * 9;
    int rem = idx & 8191;
    int ks = rem >> 12;
    int n  = (rem >> 4) & 255;
    int kh = (rem >> 3) & 1;
    int e  = rem & 7;
    int c = cc * 32 + ks * 16 + kh * 8 + e;
    w1r[idx] = (_Float16)w1[(n * 64 + c) * 9 + tt];
  } else if (bid < 2880) {                  // w2r (CI=256)
    int d = (bid - 576) * 256 + tid;
    int blk = d >> 13;
    int cc = blk / 9, tt = blk - cc * 9;
    int rem = d & 8191;
    int ks = rem >> 12;
    int n  = (rem >> 4) & 255;
    int kh = (rem >> 3) & 1;
    int e  = rem & 7;
    int c = cc * 32 + ks * 16 + kh * 8 + e;
    w2r[d] = (_Float16)w2[(n * 256 + c) * 9 + tt];
  } else if (bid < 2896) {                  // wmu2 direct, one block per k
    int k = bid - 2880;
    float s = 0.f;
#pragma unroll 4
    for (int o = 0; o < 256; ++o)
      s = fmaf(mu[k * 256 + o], w3[o * 256 + tid], s);
    wmu2[k * 256 + tid] = 2.f * s;
  } else if (bid < 2912) {                  // lgb, one block per k
    int k = bid - 2896;
    float m = mu[k * 256 + tid];
    red[tid] = m * (2.f * b3[tid] - m);
    __syncthreads();
    for (int st = 128; st > 0; st >>= 1) {
      if (tid < st) red[tid] += red[tid + st];
      __syncthreads();
    }
    if (tid == 0) lgb[k] = red[0];
  } else {                                  // t0: x -> act0 [b][HW][64] fp16
    int blk = bid - 2912;
    int b = blk >> 10;
    int p0 = (blk & 1023) << 6;
    {
      int p = tid & 63, c0 = tid >> 6;
      const float* xb = x + (size_t)b * (CIN * 65536) + p0 + p;
#pragma unroll
      for (int i = 0; i < 16; ++i) {
        int c = c0 + (i << 2);
        tile[c][p] = xb[(size_t)c * 65536];
      }
    }
    __syncthreads();
    {
      _Float16* o = act0 + (size_t)(b * 65536 + p0) * CIN;
#pragma unroll
      for (int uu = 0; uu < 2; ++uu) {
        int u = tid + (uu << 8);
        int px = u & 63, oct = u >> 6;
        half8 h;
#pragma unroll
        for (int i = 0; i < 8; ++i) h[i] = (_Float16)tile[oct * 8 + i][px];
        *(half8*)(o + px * CIN + oct * 8) = h;
      }
    }
  }
}

// ---------------------------------------------------------------------------
// Conv 3x3 (replicate pad) + bias + ReLU, 32x32x16 fp16 MFMA,
// GLOBAL-DIRECT B (r8 structure; conv main loop at its proven plateau).
// B fragments load register-direct from the L2-resident weight image (1KB
// contiguous dwordx4 each), double-buffered by parity; A staged in LDS
// (dbuf, DMA); 2 barriers per 18-tap cc-pair.
//
// conv<256> FUSES THE HEAD (r9): waves 0-1 ch 0-127, waves 2-3 ch 128-255
// (hf wave-uniform -> scalar wmu2 loads), partials meet in 8KB LDS scr,
// softmax over 16 clusters -> out. No act2 stores at all.
// All 4 batches in ONE dispatch (r11: removed 3 boundary drains, -51us).
// ---------------------------------------------------------------------------
template <int CI>
__global__ __launch_bounds__(256, 2) void k_conv(
    const _Float16* __restrict__ actin, const char* __restrict__ wr,
    const float* __restrict__ bias, _Float16* __restrict__ actout,
    const float* __restrict__ wmu2, const float* __restrict__ lgb,
    const float* __restrict__ label, float* __restrict__ outb) {
  constexpr int NC = CI / 32;
  constexpr int NT = 9 * NC;
  constexpr int QS = (CI == 256) ? 272 : 264;          // Qs fp16 stride
  constexpr int SMEM = (CI == 256) ? 77824 : 67584;    // +8KB scr if fused
  __shared__ __align__(16) char smem[SMEM];            // As(2x12288) | Qs
  auto As = (char(*)[12288])smem;
  _Float16* Qs = (_Float16*)smem;                      // [128][QS] fp16

  int tid = threadIdx.x;
  int b = blockIdx.x >> 9;
  int tile = blockIdx.x & 511;
  int txi = tile & 15, tyi = tile >> 4;
  int x0 = txi << 4, y0 = tyi << 3;
  int lane = tid & 63, wave = tid >> 6;
  int mwave = wave >> 1, nwave = wave & 1;
  int l31 = lane & 31, khalf = lane >> 5;

  f32x16 acc[2][4];
#pragma unroll
  for (int s = 0; s < 2; ++s)
#pragma unroll
    for (int nt = 0; nt < 4; ++nt)
#pragma unroll
      for (int r = 0; r < 16; ++r) acc[s][nt][r] = 0.f;

  // A staging addresses (pre-swizzled global source, linear LDS dest,
  // XOR-swizzled ds_read).
  const char* aG[3];
  int aL[3];
#pragma unroll
  for (int i = 0; i < 3; ++i) {
    int px = (wave * 3 + i) * 16 + (lane >> 2);
    int s = lane & 3;
    int pxc = min(px, 179);
    int hy = pxc / 18, hx = pxc - hy * 18;
    int y = min(max(y0 - 1 + hy, 0), 255);
    int x = min(max(x0 - 1 + hx, 0), 255);
    int q = s ^ ((pxc >> 1) & 3);
    aG[i] = (const char*)actin +
            (((size_t)(b * 65536 + y * 256 + x)) * CI + q * 8) * 2;
    aL[i] = (wave * 3 + i) * 1024;
  }

  // B global-direct per-lane pointers (ks0 / ks1), advanced 16KB per tap.
  const char* b0 = wr + ((nwave * 128 + l31) * 32 + khalf * 16);
  const char* b1 = b0 + 8192;

  // -------- prologue: A(cc=0) DMA (oldest), then preload tap0 B frags.
#pragma unroll
  for (int i = 0; i < 3; ++i) dma16(aG[i], &As[0][aL[i]]);

  half8 bf[2][2][4];   // [parity][ks][nt] — static indices after unroll
#pragma unroll
  for (int nt = 0; nt < 4; ++nt) {
    bf[0][0][nt] = *(const half8*)(b0 + nt * 1024);
    bf[0][1][nt] = *(const half8*)(b1 + nt * 1024);
  }
  b0 += 16384; b1 += 16384;
  asm volatile("s_waitcnt vmcnt(8)" ::: "memory");
  __builtin_amdgcn_s_barrier();

  for (int c2 = 0; c2 < NC; c2 += 2) {
    bool last2 = (c2 + 2 >= NC);
#pragma unroll
    for (int u = 0; u < 18; ++u) {
      int t = (u < 9) ? u : u - 9;
      int pr = u & 1;
      // ---- A prefetch (issued FIRST so it is oldest in the queue) ----
      if (u == 6) {
#pragma unroll
        for (int i = 0; i < 3; ++i)
          dma16(aG[i] + (c2 + 1) * 64, &As[1][aL[i]]);
      }
      if (u == 15 && !last2) {
#pragma unroll
        for (int i = 0; i < 3; ++i)
          dma16(aG[i] + (c2 + 2) * 64, &As[0][aL[i]]);
      }
      // ---- B prefetch for tap j+1 into parity pr^1 ----
      if (!(last2 && u == 17)) {
#pragma unroll
        for (int nt = 0; nt < 4; ++nt) {
          bf[pr ^ 1][0][nt] = *(const half8*)(b0 + nt * 1024);
          bf[pr ^ 1][1][nt] = *(const half8*)(b1 + nt * 1024);
        }
        b0 += 16384; b1 += 16384;
      }
      // ---- compute: JIT A fragment reads + 16 MFMA ----
      const char* Ab = As[(u >= 9) ? 1 : 0];
      int dy = t / 3, dx = t - dy * 3;
      half8 af[2][2];
#pragma unroll
      for (int s = 0; s < 2; ++s) {
        int px = (mwave * 4 + s * 2 + (l31 >> 4) + dy) * 18 + (l31 & 15) + dx;
        int sw = ((px >> 1) & 3) << 4;
#pragma unroll
        for (int ks = 0; ks < 2; ++ks) {
          int q = (ks * 2 + khalf) << 4;
          af[ks][s] = *(const half8*)(Ab + px * 64 + (q ^ sw));
        }
      }
      __builtin_amdgcn_s_setprio(1);
#pragma unroll
      for (int ks = 0; ks < 2; ++ks)
#pragma unroll
        for (int s = 0; s < 2; ++s)
#pragma unroll
          for (int nt = 0; nt < 4; ++nt)
            acc[s][nt] = __builtin_amdgcn_mfma_f32_32x32x16_f16(
                af[ks][s], bf[pr][ks][nt], acc[s][nt], 0, 0, 0);
      __builtin_amdgcn_s_setprio(0);
      // ---- per-cc boundary sync only ----
      if (u == 8) {
        asm volatile("s_waitcnt vmcnt(8) lgkmcnt(0)" ::: "memory");
        __builtin_amdgcn_s_barrier();
      }
      if (u == 17 && !last2) {
        asm volatile("s_waitcnt vmcnt(8) lgkmcnt(0)" ::: "memory");
        __builtin_amdgcn_s_barrier();
      }
    }
  }
  __syncthreads();   // WAR: Qs overlays As (all waves' reads done)

  // ---- stage bias+relu'd activation tile to LDS [128][QS] fp16 ----
  // C/D: col = lane&31, row = (r&3) + 8*(r>>2) + 4*(lane>>5)
#pragma unroll
  for (int s = 0; s < 2; ++s)
#pragma unroll
    for (int nt = 0; nt < 4; ++nt) {
      int n = nwave * 128 + nt * 32 + l31;
      float bn = bias[n];
#pragma unroll
      for (int r = 0; r < 16; ++r) {
        int mrow = (r & 3) + 8 * (r >> 2) + 4 * khalf;
        int p = (mwave * 4 + s * 2 + (mrow >> 4)) * 16 + (mrow & 15);
        Qs[p * QS + n] = (_Float16)fmaxf(acc[s][nt][r] + bn, 0.f);
      }
    }
  __syncthreads();

  if (CI == 64) {
    // ---- conv1: coalesced act1 stores ----
    _Float16* gout = actout + (((size_t)(b * 65536 + y0 * 256 + x0)) << 8);
#pragma unroll
    for (int i = 0; i < 16; ++i) {
      int f = tid + (i << 8);
      int p = f >> 5, o = f & 31;
      half8 v = *(const half8*)&Qs[p * QS + o * 8];
      *(half8*)(gout + (((p >> 4) * 256 + (p & 15)) << 8) + o * 8) = v;
    }
  } else {
    // ---- conv2: FUSED HEAD. waves 0-1: ch 0-127; waves 2-3: ch 128-255.
    float* scr = (float*)(smem + 69632);     // [16][128] partials, 8KB
    int hf = __builtin_amdgcn_readfirstlane(wave >> 1);  // wave-uniform
    int px = ((wave & 1) << 6) + lane;       // 0..127
    const _Float16* qrow = Qs + px * QS + hf * 128;
    float cr[16];
#pragma unroll
    for (int k = 0; k < 16; ++k) cr[k] = 0.f;
#pragma unroll 2
    for (int c8 = 0; c8 < 16; ++c8) {
      half8 h = *(const half8*)(qrow + c8 * 8);
      float a0 = (float)h[0], a1 = (float)h[1], a2 = (float)h[2],
            a3 = (float)h[3], a4 = (float)h[4], a5 = (float)h[5],
            a6 = (float)h[6], a7 = (float)h[7];
#pragma unroll
      for (int k = 0; k < 16; ++k) {
        const float* w = wmu2 + (k << 8) + (hf << 7) + (c8 << 3);  // scalar
        float c0 = cr[k];
        c0 = fmaf(a0, w[0], c0);
        c0 = fmaf(a1, w[1], c0);
        c0 = fmaf(a2, w[2], c0);
        c0 = fmaf(a3, w[3], c0);
        c0 = fmaf(a4, w[4], c0);
        c0 = fmaf(a5, w[5], c0);
        c0 = fmaf(a6, w[6], c0);
        c0 = fmaf(a7, w[7], c0);
        cr[k] = c0;
      }
    }
    if (hf) {
#pragma unroll
      for (int k = 0; k < 16; ++k) scr[k * 128 + px] = cr[k];
    }
    __syncthreads();
    if (!hf) {
#pragma unroll
      for (int k = 0; k < 16; ++k) cr[k] += scr[k * 128 + px] + lgb[k];
      float mx = cr[0];
#pragma unroll
      for (int k = 1; k < 16; ++k) mx = fmaxf(mx, cr[k]);
      float num = 0.f, den = 0.f;
#pragma unroll
      for (int k = 0; k < 16; ++k) {
        float e = __expf(cr[k] - mx);
        num = fmaf(e, label[k], num);
        den += e;
      }
      outb[(size_t)b * 65536 + (y0 + (px >> 4)) * 256 + (x0 + (px & 15))] =
          num / den;
    }
  }
}

// ---------------------------------------------------------------------------
extern "C" void kernel_launch(void* const* d_in, const int* in_sizes, int n_in,
                              void* d_out, int out_size, void* d_ws, size_t ws_size,
                              hipStream_t stream) {
  const float* x  = (const float*)d_in[0];
  const float* w1 = (const float*)d_in[1];
  const float* b1 = (const float*)d_in[2];
  const float* w2 = (const float*)d_in[3];
  const float* b2 = (const float*)d_in[4];
  const float* w3 = (const float*)d_in[5];
  const float* b3 = (const float*)d_in[6];
  const float* mu = (const float*)d_in[7];
  const float* label = (const float*)d_in[8];
  float* out = (float*)d_out;

  char* ws = (char*)d_ws;
  _Float16* w1r  = (_Float16*)(ws + OFF_W1R);
  _Float16* w2r  = (_Float16*)(ws + OFF_W2R);
  float*    wmu2 = (float*)   (ws + OFF_WMU);
  float*    lgb  = (float*)   (ws + OFF_LGB);
  _Float16* act0 = (_Float16*)(ws + OFF_ACT0);   // [4][HW][64], 32 MB
  _Float16* act1 = (_Float16*)(ws + OFF_ACT1);   // [4][HW][256], 128 MB

  // prep (weights + head constants + t0) in one dispatch; wmu2 computed
  // directly (no partial-reduction second dispatch).
  k_prep<<<7008, 256, 0, stream>>>(w1, w2, w3, b3, mu, x,
                                   w1r, w2r, wmu2, lgb, act0);
  k_conv<64><<<2048, 256, 0, stream>>>(act0, (const char*)w1r, b1, act1,
                                       nullptr, nullptr, nullptr, nullptr);
  // all 4 batches in one dispatch (no act2 aliasing since head fusion)
  k_conv<256><<<2048, 256, 0, stream>>>(act1, (const char*)w2r, b2, nullptr,
                                        wmu2, lgb, label, out);
}